// Round 10
// baseline (122.613 us; speedup 1.0000x reference)
//
#include <hip/hip_runtime.h>

// Problem constants (match reference)
#define NB 32768   // batch rows
#define NF 256     // features
#define NH 8       // hidden dim
#define ROWS_PER_BLOCK 8

// One thread per feature; 96 MLP params in registers; FULL unroll (rolling
// spills — round 8). KEY CHANGE vs rounds 3-9: only 8 rows per block, so the
// unrolled compute body is ~6.5 KB (vs ~28 KB) and stays warm in L1I — the
// round-3..9 kernels were stuck at ~29% VALU issue with every data-path fix
// neutral, consistent with instruction-fetch limiting. Register pressure
// ~140 -> launch_bounds(256,3): 3 blocks/CU resident (3 waves/SIMD).
// Results to LDS (8 KB); one barrier; store+reduce phase: each wave handles
// 2 rows — ds_read float4, coalesced dwordx4 out_w store, sum butterfly.
__global__ __launch_bounds__(256, 3) void NAM_49314814493074_kernel(
    const float* __restrict__ input,   // [B, F]
    const float* __restrict__ W1,      // [F, 8]
    const float* __restrict__ b1,      // [F, 8]
    const float* __restrict__ W2,      // [F, 8, 8]
    const float* __restrict__ b2,      // [F, 8]
    const float* __restrict__ W3,      // [F, 8]
    float* __restrict__ out_sum,       // [B]
    float* __restrict__ out_w)         // [B, F]
{
    __shared__ float sred[ROWS_PER_BLOCK][NF];   // 8 KB

    const int f = threadIdx.x;                  // feature index 0..255
    const int row0 = blockIdx.x * ROWS_PER_BLOCK;

    const float* xin = input + (size_t)row0 * NF + f;

    // ---- prefetch this block's 8 x values (all loads in flight) ----
    float xv[ROWS_PER_BLOCK];
    #pragma unroll
    for (int r = 0; r < ROWS_PER_BLOCK; ++r)
        xv[r] = xin[(size_t)r * NF];

    // ---- per-feature params into registers ----
    float w1[NH], bb1[NH], bb2[NH], w3[NH];
    float w2[NH][NH];
    {
        const float4* p1  = reinterpret_cast<const float4*>(W1 + (size_t)f * NH);
        const float4* pb1 = reinterpret_cast<const float4*>(b1 + (size_t)f * NH);
        const float4* pb2 = reinterpret_cast<const float4*>(b2 + (size_t)f * NH);
        const float4* p3  = reinterpret_cast<const float4*>(W3 + (size_t)f * NH);
        float4 a, b;
        a = p1[0]; b = p1[1];
        w1[0]=a.x; w1[1]=a.y; w1[2]=a.z; w1[3]=a.w; w1[4]=b.x; w1[5]=b.y; w1[6]=b.z; w1[7]=b.w;
        a = pb1[0]; b = pb1[1];
        bb1[0]=a.x; bb1[1]=a.y; bb1[2]=a.z; bb1[3]=a.w; bb1[4]=b.x; bb1[5]=b.y; bb1[6]=b.z; bb1[7]=b.w;
        a = pb2[0]; b = pb2[1];
        bb2[0]=a.x; bb2[1]=a.y; bb2[2]=a.z; bb2[3]=a.w; bb2[4]=b.x; bb2[5]=b.y; bb2[6]=b.z; bb2[7]=b.w;
        a = p3[0]; b = p3[1];
        w3[0]=a.x; w3[1]=a.y; w3[2]=a.z; w3[3]=a.w; w3[4]=b.x; w3[5]=b.y; w3[6]=b.z; w3[7]=b.w;

        const float4* p2 = reinterpret_cast<const float4*>(W2 + (size_t)f * NH * NH);
        #pragma unroll
        for (int h = 0; h < NH; ++h) {
            float4 c0 = p2[h * 2 + 0];
            float4 c1 = p2[h * 2 + 1];
            w2[h][0]=c0.x; w2[h][1]=c0.y; w2[h][2]=c0.z; w2[h][3]=c0.w;
            w2[h][4]=c1.x; w2[h][5]=c1.y; w2[h][6]=c1.z; w2[h][7]=c1.w;
        }
    }

    // ---- compute 8 rows, fully unrolled (~6.5 KB of code) ----
    #pragma unroll
    for (int r = 0; r < ROWS_PER_BLOCK; ++r) {
        const float x = xv[r];

        float h1[NH];
        #pragma unroll
        for (int h = 0; h < NH; ++h)
            h1[h] = fmaxf(fmaf(x, w1[h], bb1[h]), 0.0f);

        float acc[NH];
        #pragma unroll
        for (int k = 0; k < NH; ++k)       // fold init into h=0 FMA
            acc[k] = fmaf(h1[0], w2[0][k], bb2[k]);
        #pragma unroll
        for (int h = 1; h < NH; ++h) {
            #pragma unroll
            for (int k = 0; k < NH; ++k)
                acc[k] = fmaf(h1[h], w2[h][k], acc[k]);
        }

        float s = 0.0f;
        #pragma unroll
        for (int k = 0; k < NH; ++k)
            s = fmaf(fmaxf(acc[k], 0.0f), w3[k], s);

        sred[r][f] = s;
    }

    __syncthreads();

    // ---- store + reduce phase: wave w handles rows [2w, 2w+2) ----
    const int wave = threadIdx.x >> 6;
    const int lane = threadIdx.x & 63;
    #pragma unroll
    for (int rr = 0; rr < ROWS_PER_BLOCK / 4; ++rr) {
        const int r = wave * (ROWS_PER_BLOCK / 4) + rr;
        const float4 q = reinterpret_cast<const float4*>(&sred[r][0])[lane];
        reinterpret_cast<float4*>(out_w + (size_t)(row0 + r) * NF)[lane] = q;
        float v = q.x + q.y + q.z + q.w;
        #pragma unroll
        for (int off = 32; off > 0; off >>= 1)
            v += __shfl_xor(v, off, 64);
        if (lane == 0)
            out_sum[row0 + r] = v;
    }
}

extern "C" void kernel_launch(void* const* d_in, const int* in_sizes, int n_in,
                              void* d_out, int out_size, void* d_ws, size_t ws_size,
                              hipStream_t stream) {
    const float* input = (const float*)d_in[0];
    const float* W1    = (const float*)d_in[1];
    const float* b1    = (const float*)d_in[2];
    const float* W2    = (const float*)d_in[3];
    const float* b2    = (const float*)d_in[4];
    const float* W3    = (const float*)d_in[5];

    float* out = (float*)d_out;          // [B] sums, then [B,F] w
    float* out_sum = out;
    float* out_w   = out + NB;

    dim3 grid(NB / ROWS_PER_BLOCK);      // 4096 blocks
    dim3 block(NF);                      // 256 threads = 1 per feature
    NAM_49314814493074_kernel<<<grid, block, 0, stream>>>(
        input, W1, b1, W2, b2, W3, out_sum, out_w);
}

// Round 12
// 109.678 us; speedup vs baseline: 1.1179x; 1.1179x over previous
//
#include <hip/hip_runtime.h>

// Problem constants (match reference)
#define NB 32768   // batch rows
#define NF 256     // features
#define NH 8       // hidden dim
#define RPB 32     // rows per block

// Round-10's VGPR=64 counter proved the compiler never keeps the 96 MLP
// params register-resident: it re-materializes param loads per row and sinks
// x-prefetches to just-before-use (why rounds 3/5/7/9 were all neutral).
// This kernel takes both load streams away from the scheduler:
//  1. x-tile (32x256 = 32 KB) staged into LDS via global_load_lds DMA —
//     un-sinkable, drained once by __syncthreads. Compute reads x via
//     conflict-free ds_read_b32 and overwrites the slot with s in place
//     (each thread touches only its own column -> race-free, one buffer).
//  2. Params loaded as 11 float4s then PINNED with empty asm "+v" — values
//     now originate from asm, so loads can't be re-materialized; ~90 VGPR
//     live under the (256,3) cap (~170): no spill, ~5 blocks/CU resident.

typedef float f4 __attribute__((ext_vector_type(4)));
typedef __attribute__((address_space(1))) const unsigned int gu32;
typedef __attribute__((address_space(3))) unsigned int lu32;

__global__ __launch_bounds__(256, 3) void NAM_49314814493074_kernel(
    const float* __restrict__ input,   // [B, F]
    const float* __restrict__ W1,      // [F, 8]
    const float* __restrict__ b1,      // [F, 8]
    const float* __restrict__ W2,      // [F, 8, 8]
    const float* __restrict__ b2,      // [F, 8]
    const float* __restrict__ W3,      // [F, 8]
    float* __restrict__ out_sum,       // [B]
    float* __restrict__ out_w)         // [B, F]
{
    __shared__ float xs[RPB][NF];      // 32 KB: staged x, overwritten by s

    const int f    = threadIdx.x;      // feature 0..255
    const int wave = f >> 6;
    const int lane = f & 63;
    const int row0 = blockIdx.x * RPB;

    // ---- 1. async-stage the x tile: 32 DMA ops, issued before anything ----
    {
        const float* g = input + (size_t)row0 * NF + wave * 64 + lane; // per-lane
        float* l = &xs[0][wave * 64];                                  // wave-uniform
        #pragma unroll
        for (int r = 0; r < RPB; ++r) {
            __builtin_amdgcn_global_load_lds((gu32*)(g + (size_t)r * NF),
                                             (lu32*)(l + r * NF), 4, 0, 0);
        }
    }

    // ---- 2. params: 11 dwordx4 loads, pinned into registers ----
    f4 w1a, w1b, b1a, b1b, b2a, b2b, w3a, w3b, w2v[16];
    {
        const f4* pW1 = reinterpret_cast<const f4*>(W1 + (size_t)f * NH);
        const f4* pB1 = reinterpret_cast<const f4*>(b1 + (size_t)f * NH);
        const f4* pB2 = reinterpret_cast<const f4*>(b2 + (size_t)f * NH);
        const f4* pW3 = reinterpret_cast<const f4*>(W3 + (size_t)f * NH);
        const f4* pW2 = reinterpret_cast<const f4*>(W2 + (size_t)f * NH * NH);
        w1a = pW1[0]; w1b = pW1[1];
        b1a = pB1[0]; b1b = pB1[1];
        b2a = pB2[0]; b2b = pB2[1];
        w3a = pW3[0]; w3b = pW3[1];
        #pragma unroll
        for (int i = 0; i < 16; ++i) w2v[i] = pW2[i];
    }
    asm volatile("" : "+v"(w1a), "+v"(w1b), "+v"(b1a), "+v"(b1b),
                      "+v"(b2a), "+v"(b2b), "+v"(w3a), "+v"(w3b));
    asm volatile("" : "+v"(w2v[0]), "+v"(w2v[1]), "+v"(w2v[2]), "+v"(w2v[3]),
                      "+v"(w2v[4]), "+v"(w2v[5]), "+v"(w2v[6]), "+v"(w2v[7]),
                      "+v"(w2v[8]), "+v"(w2v[9]), "+v"(w2v[10]), "+v"(w2v[11]),
                      "+v"(w2v[12]), "+v"(w2v[13]), "+v"(w2v[14]), "+v"(w2v[15]));

    __syncthreads();   // drains vmcnt(0): staging + params complete

    // ---- 3. compute 32 rows, fully unrolled, pure-register math ----
    #pragma unroll
    for (int r = 0; r < RPB; ++r) {
        const float x = xs[r][f];      // ds_read_b32, conflict-free

        float h1[NH];
        #pragma unroll
        for (int h = 0; h < NH; ++h)
            h1[h] = fmaxf(fmaf(x, (h < 4 ? w1a[h] : w1b[h - 4]),
                                  (h < 4 ? b1a[h] : b1b[h - 4])), 0.0f);

        float acc[NH];
        #pragma unroll
        for (int k = 0; k < NH; ++k)   // fold init into h=0 FMA
            acc[k] = fmaf(h1[0], w2v[(k >> 2)][k & 3],
                          (k < 4 ? b2a[k] : b2b[k - 4]));
        #pragma unroll
        for (int h = 1; h < NH; ++h) {
            #pragma unroll
            for (int k = 0; k < NH; ++k)
                acc[k] = fmaf(h1[h], w2v[h * 2 + (k >> 2)][k & 3], acc[k]);
        }

        float s = 0.0f;
        #pragma unroll
        for (int k = 0; k < NH; ++k)
            s = fmaf(fmaxf(acc[k], 0.0f), (k < 4 ? w3a[k] : w3b[k - 4]), s);

        xs[r][f] = s;                  // in-place: own column only
    }

    __syncthreads();

    // ---- 4. store + reduce: wave w handles rows [8w, 8w+8) ----
    #pragma unroll
    for (int rr = 0; rr < RPB / 4; ++rr) {
        const int r = wave * (RPB / 4) + rr;
        const float4 q = reinterpret_cast<const float4*>(&xs[r][0])[lane];
        reinterpret_cast<float4*>(out_w + (size_t)(row0 + r) * NF)[lane] = q;
        float v = q.x + q.y + q.z + q.w;
        #pragma unroll
        for (int off = 32; off > 0; off >>= 1)
            v += __shfl_xor(v, off, 64);
        if (lane == 0)
            out_sum[row0 + r] = v;
    }
}

extern "C" void kernel_launch(void* const* d_in, const int* in_sizes, int n_in,
                              void* d_out, int out_size, void* d_ws, size_t ws_size,
                              hipStream_t stream) {
    const float* input = (const float*)d_in[0];
    const float* W1    = (const float*)d_in[1];
    const float* b1    = (const float*)d_in[2];
    const float* W2    = (const float*)d_in[3];
    const float* b2    = (const float*)d_in[4];
    const float* W3    = (const float*)d_in[5];

    float* out = (float*)d_out;          // [B] sums, then [B,F] w
    float* out_sum = out;
    float* out_w   = out + NB;

    dim3 grid(NB / RPB);                 // 1024 blocks
    dim3 block(NF);                      // 256 threads = 1 per feature
    NAM_49314814493074_kernel<<<grid, block, 0, stream>>>(
        input, W1, b1, W2, b2, W3, out_sum, out_w);
}